// Round 2
// baseline (711.077 us; speedup 1.0000x reference)
//
#include <hip/hip_runtime.h>
#include <math.h>

typedef unsigned short u16;
typedef unsigned int u32;
typedef short bf16x8 __attribute__((ext_vector_type(8)));
typedef unsigned short u16x8 __attribute__((ext_vector_type(8)));
typedef float f32x4 __attribute__((ext_vector_type(4)));

#define DEV static __device__ __forceinline__

#define BB 256
#define NN 181
#define DD 512
#define HH 8
#define DKk 64
#define DFF 2048
#define NPAD 192
#define MTOT (BB*NN)          // 46336
#define MHALF (MTOT/2)        // 23168 (= 181 tiles of 128)
#define QKV_ELEMS (23724032u) // B*H*N*64
#define WS_NEEDED 196384768ull

DEV u16 f2bf(float f){
  u32 u = __float_as_uint(f);
  u32 r = (u + 0x7FFFu + ((u >> 16) & 1u)) >> 16;
  return (u16)r;
}
DEV float bf2f(u16 h){ return __uint_as_float(((u32)h) << 16); }
DEV bf16x8 as_bf(u16x8 v){ return __builtin_bit_cast(bf16x8, v); }

DEV void gl_lds16(const u16* g, u16* l){
  __builtin_amdgcn_global_load_lds(
      (const __attribute__((address_space(1))) unsigned int*)g,
      (__attribute__((address_space(3))) unsigned int*)l, 16, 0, 0);
}

// ---------------- cast fp32 -> bf16, 8 elems/thread ----------------
__global__ __launch_bounds__(256) void cast_bf16(const float* __restrict__ in,
                                                 u16* __restrict__ out, int n8){
  int i = blockIdx.x*256 + threadIdx.x;
  if (i >= n8) return;
  const float4* p = reinterpret_cast<const float4*>(in + (size_t)i*8);
  float4 a = p[0], b = p[1];
  u16x8 o;
  o[0]=f2bf(a.x); o[1]=f2bf(a.y); o[2]=f2bf(a.z); o[3]=f2bf(a.w);
  o[4]=f2bf(b.x); o[5]=f2bf(b.y); o[6]=f2bf(b.z); o[7]=f2bf(b.w);
  *reinterpret_cast<u16x8*>(out + (size_t)i*8) = o;
}

// ---------------- attention bias table [2][192][192] ----------------
__global__ __launch_bounds__(256) void build_bias(const int* __restrict__ mask,
                                                  float* __restrict__ biasA){
  int idx = blockIdx.x*256 + threadIdx.x;
  if (idx >= 2*NPAD*NPAD) return;
  int g = idx / (NPAD*NPAD);
  int rem = idx % (NPAD*NPAD);
  int q = rem / NPAD, k = rem % NPAD;
  float v;
  if (k >= NN) v = -INFINITY;            // padded keys: excluded
  else if (q >= NN) v = 0.f;             // padded query rows: benign
  else {
    bool qv = q < 121, kv = k < 121;
    bool allowed = (g == 0) ? (qv != kv) : (qv == kv);
    if (!allowed) v = -INFINITY;
    else {
      int mb = (g == 0 && !qv) ? mask[k*NN + q]   // r1c uses transposed mask
                               : mask[q*NN + k];
      v = mb ? -1e9f : 0.f;
    }
  }
  biasA[idx] = v;
}

__global__ __launch_bounds__(256) void concat3(const float* __restrict__ a,
                                               const float* __restrict__ b,
                                               const float* __restrict__ c,
                                               float* __restrict__ out){
  int i = blockIdx.x*256 + threadIdx.x;
  if (i < 512){ out[i] = a[i]; out[512+i] = b[i]; out[1024+i] = c[i]; }
}

// ---------------- GEMM C = A(MxK) * B(NxK)^T, bf16 MFMA ----------------
// EPI 0: QKV scatter (+0.125 on Q), 1: +bo+x -> r1 bf16, 2: relu -> ff1 bf16,
// EPI 3: +b2+h(bf16) -> s2 bf16
template<int EPI>
__global__ __launch_bounds__(256) void gemm_nt(
    const u16* __restrict__ A, const u16* __restrict__ Bw,
    int M, int N, int K,
    const float* __restrict__ bias,
    u16* __restrict__ outb,
    const float* __restrict__ resf,
    const u16* __restrict__ resb)
{
  __shared__ u16 As[128*64];
  __shared__ u16 Bs[128*64];
  const int tid = threadIdx.x, lane = tid & 63, wave = tid >> 6;
  const int lo = lane & 15, hi = lane >> 4;
  const int mt = blockIdx.y, nt = blockIdx.x;
  const u16* Ab = A + (size_t)mt*128*K;
  const u16* Bb = Bw + (size_t)nt*128*K;
  const int wm = (wave >> 1)*64, wn = (wave & 1)*64;
  const int sr = wave*8 + (lane >> 3);     // + i*32 staging row
  const int sc = (lane & 7)*8;             // staging col

  f32x4 acc[4][4];
  #pragma unroll
  for (int m=0;m<4;++m)
    #pragma unroll
    for (int n=0;n<4;++n) acc[m][n] = f32x4{0.f,0.f,0.f,0.f};

  for (int k0 = 0; k0 < K; k0 += 64){
    __syncthreads();
    #pragma unroll
    for (int i=0;i<4;++i){
      int r = i*32 + sr;
      gl_lds16(Ab + (size_t)r*K + k0 + sc, &As[i*2048 + wave*512]);
      gl_lds16(Bb + (size_t)r*K + k0 + sc, &Bs[i*2048 + wave*512]);
    }
    __syncthreads();
    #pragma unroll
    for (int kk=0;kk<2;++kk){
      bf16x8 af[4], bw[4];
      #pragma unroll
      for (int m=0;m<4;++m)
        af[m] = *reinterpret_cast<const bf16x8*>(&As[(wm+m*16+lo)*64 + kk*32 + hi*8]);
      #pragma unroll
      for (int n=0;n<4;++n)
        bw[n] = *reinterpret_cast<const bf16x8*>(&Bs[(wn+n*16+lo)*64 + kk*32 + hi*8]);
      #pragma unroll
      for (int m=0;m<4;++m)
        #pragma unroll
        for (int n=0;n<4;++n)
          acc[m][n] = __builtin_amdgcn_mfma_f32_16x16x32_bf16(af[m], bw[n], acc[m][n], 0,0,0);
    }
  }

  #pragma unroll
  for (int m=0;m<4;++m){
    const int rowb = mt*128 + wm + m*16 + hi*4;
    #pragma unroll
    for (int n=0;n<4;++n){
      const int gcol = nt*128 + wn + n*16 + lo;
      const float bv = bias[gcol];
      #pragma unroll
      for (int r=0;r<4;++r){
        const int row = rowb + r;
        float v = acc[m][n][r] + bv;
        if constexpr (EPI == 0){
          int which = gcol >> 9;
          int hh = (gcol >> 6) & 7;
          int d  = gcol & 63;
          if (which == 0) v *= 0.125f;               // fold 1/sqrt(DK)
          int bi = row / NN, ni = row % NN;
          outb[(size_t)which*QKV_ELEMS + (((size_t)bi*HH + hh)*NN + ni)*DKk + d] = f2bf(v);
        } else if constexpr (EPI == 1){
          v += resf[(size_t)row*N + gcol];
          outb[(size_t)row*N + gcol] = f2bf(v);
        } else if constexpr (EPI == 2){
          outb[(size_t)row*N + gcol] = f2bf(fmaxf(v, 0.f));
        } else {
          v += bf2f(resb[(size_t)row*N + gcol]);
          outb[(size_t)row*N + gcol] = f2bf(v);
        }
      }
    }
  }
}

// ---------------- fused segment attention ----------------
// grid = B*H blocks, 256 threads (4 waves). Dense 181-key attention with
// additive bias table handling segment structure + mask (+transposed r1c mask).
__global__ __launch_bounds__(256) void attn_kernel(
    const u16* __restrict__ Qg, const u16* __restrict__ Kg, const u16* __restrict__ Vg,
    const float* __restrict__ biasA, u16* __restrict__ ctx)
{
  __shared__ u16 Kb[NPAD*72];      // K  [192][72] padded
  __shared__ u16 Vt[64*200];       // V^T [64][200] padded
  __shared__ u16 Pl[4*16*200];     // per-wave P bounce; also V row staging
  const int tid = threadIdx.x, lane = tid & 63, wave = tid >> 6;
  const int lo = lane & 15, hi = lane >> 4;
  const int bh = blockIdx.x;
  const int h = bh & 7, g = h >> 2, b = bh >> 3;
  const size_t base = (size_t)bh * NN * DKk;

  // stage K [192][72], zero pad rows
  #pragma unroll
  for (int it=0; it<6; ++it){
    int row = it*32 + (tid >> 3);
    int cb = (tid & 7)*8;
    u16x8 val = {0,0,0,0,0,0,0,0};
    if (row < NN) val = *reinterpret_cast<const u16x8*>(Kg + base + (size_t)row*DKk + cb);
    *reinterpret_cast<u16x8*>(&Kb[row*72 + cb]) = val;
  }
  // stage V rows into Pl scratch [192][64]
  #pragma unroll
  for (int it=0; it<6; ++it){
    int row = it*32 + (tid >> 3);
    int cb = (tid & 7)*8;
    u16x8 val = {0,0,0,0,0,0,0,0};
    if (row < NN) val = *reinterpret_cast<const u16x8*>(Vg + base + (size_t)row*DKk + cb);
    *reinterpret_cast<u16x8*>(&Pl[row*64 + cb]) = val;
  }
  __syncthreads();
  // transpose V -> Vt[64][200]
  #pragma unroll
  for (int j=0;j<6;++j){
    int task = j*256 + tid;          // 0..1535
    int d = task & 63;
    int nc = task >> 6;              // 0..23
    u16x8 tv;
    #pragma unroll
    for (int i=0;i<8;++i) tv[i] = Pl[(nc*8+i)*64 + d];
    *reinterpret_cast<u16x8*>(&Vt[d*200 + nc*8]) = tv;
  }
  __syncthreads();

  u16* pw = Pl + wave*16*200;

  for (int rb = wave; rb < 12; rb += 4){
    const int q0 = rb*16;
    const int qrow = q0 + lo;
    // Q A-frags from global (Q pre-scaled by 1/8)
    bf16x8 qa[2];
    #pragma unroll
    for (int kk=0;kk<2;++kk){
      u16x8 val = {0,0,0,0,0,0,0,0};
      if (qrow < NN) val = *reinterpret_cast<const u16x8*>(Qg + base + (size_t)qrow*DKk + kk*32 + hi*8);
      qa[kk] = as_bf(val);
    }
    // scores S[q0+hi*4+r][c*16+lo]
    f32x4 s[12];
    #pragma unroll
    for (int c=0;c<12;++c){
      f32x4 a = f32x4{0.f,0.f,0.f,0.f};
      #pragma unroll
      for (int kk=0;kk<2;++kk){
        bf16x8 kb = *reinterpret_cast<const bf16x8*>(&Kb[(c*16+lo)*72 + kk*32 + hi*8]);
        a = __builtin_amdgcn_mfma_f32_16x16x32_bf16(qa[kk], kb, a, 0,0,0);
      }
      s[c] = a;
    }
    // bias add
    const float* brow = biasA + ((size_t)g*NPAD + q0 + hi*4)*NPAD + lo;
    #pragma unroll
    for (int r=0;r<4;++r)
      #pragma unroll
      for (int c=0;c<12;++c)
        s[c][r] += brow[r*NPAD + c*16];
    // softmax (rows live in 16-lane groups)
    float inv[4];
    #pragma unroll
    for (int r=0;r<4;++r){
      float m = s[0][r];
      #pragma unroll
      for (int c=1;c<12;++c) m = fmaxf(m, s[c][r]);
      #pragma unroll
      for (int off=1; off<16; off<<=1) m = fmaxf(m, __shfl_xor(m, off, 64));
      float t = 0.f;
      #pragma unroll
      for (int c=0;c<12;++c){ float e = __expf(s[c][r] - m); s[c][r] = e; t += e; }
      #pragma unroll
      for (int off=1; off<16; off<<=1) t += __shfl_xor(t, off, 64);
      inv[r] = 1.0f / t;
    }
    // write P (bf16) into per-wave LDS, C-layout -> A-layout bounce
    #pragma unroll
    for (int c=0;c<12;++c)
      #pragma unroll
      for (int r=0;r<4;++r)
        pw[(hi*4+r)*200 + c*16 + lo] = f2bf(s[c][r] * inv[r]);
    asm volatile("s_waitcnt lgkmcnt(0)" ::: "memory");
    __builtin_amdgcn_sched_barrier(0);
    // PV
    bf16x8 pa[6];
    #pragma unroll
    for (int c6=0;c6<6;++c6)
      pa[c6] = *reinterpret_cast<const bf16x8*>(&pw[lo*200 + c6*32 + hi*8]);
    #pragma unroll
    for (int dt=0;dt<4;++dt){
      f32x4 a = f32x4{0.f,0.f,0.f,0.f};
      #pragma unroll
      for (int c6=0;c6<6;++c6){
        bf16x8 vb = *reinterpret_cast<const bf16x8*>(&Vt[(dt*16+lo)*200 + c6*32 + hi*8]);
        a = __builtin_amdgcn_mfma_f32_16x16x32_bf16(pa[c6], vb, a, 0,0,0);
      }
      // store ctx [B,N,D] bf16 at D-offset h*64
      #pragma unroll
      for (int r=0;r<4;++r){
        int q = q0 + hi*4 + r;
        if (q < NN)
          ctx[((size_t)b*NN + q)*DD + h*DKk + dt*16 + lo] = f2bf(a[r]);
      }
    }
  }
}

// ---------------- LayerNorm over D=512, one wave per row ----------------
template<int OUTF32>
__global__ __launch_bounds__(256) void ln_kernel(
    const u16* __restrict__ in, const float* __restrict__ gamma,
    const float* __restrict__ beta, void* __restrict__ outp)
{
  const int row = blockIdx.x*4 + (threadIdx.x >> 6);
  const int lane = threadIdx.x & 63;
  u16x8 rv = *reinterpret_cast<const u16x8*>(in + (size_t)row*512 + lane*8);
  float x[8]; float s = 0.f, s2 = 0.f;
  #pragma unroll
  for (int i=0;i<8;++i){ x[i] = bf2f(rv[i]); s += x[i]; s2 += x[i]*x[i]; }
  #pragma unroll
  for (int off=32; off>=1; off>>=1){ s += __shfl_xor(s, off, 64); s2 += __shfl_xor(s2, off, 64); }
  const float mu = s * (1.f/512.f);
  const float var = s2 * (1.f/512.f) - mu*mu;
  const float rstd = rsqrtf(var + 1e-5f);
  float4 ga = *reinterpret_cast<const float4*>(gamma + lane*8);
  float4 gb = *reinterpret_cast<const float4*>(gamma + lane*8 + 4);
  float4 ba = *reinterpret_cast<const float4*>(beta + lane*8);
  float4 bb = *reinterpret_cast<const float4*>(beta + lane*8 + 4);
  float gg[8] = {ga.x,ga.y,ga.z,ga.w,gb.x,gb.y,gb.z,gb.w};
  float bt[8] = {ba.x,ba.y,ba.z,ba.w,bb.x,bb.y,bb.z,bb.w};
  if constexpr (OUTF32){
    float o[8];
    #pragma unroll
    for (int i=0;i<8;++i) o[i] = (x[i]-mu)*rstd*gg[i] + bt[i];
    float4* op = reinterpret_cast<float4*>((float*)outp + (size_t)row*512 + lane*8);
    op[0] = make_float4(o[0],o[1],o[2],o[3]);
    op[1] = make_float4(o[4],o[5],o[6],o[7]);
  } else {
    u16x8 o;
    #pragma unroll
    for (int i=0;i<8;++i) o[i] = f2bf((x[i]-mu)*rstd*gg[i] + bt[i]);
    *reinterpret_cast<u16x8*>((u16*)outp + (size_t)row*512 + lane*8) = o;
  }
}

// ---------------- launch ----------------
// Workspace map (total 196,384,768 B):
//   [0        ..  1572864) wqkv bf16
//   [1572864  ..  2097152) wo_b bf16
//   [2097152  ..  4194304) w1_b bf16
//   [4194304  ..  6291456) w2_b bf16
//   [6291456  ..  6586368) biasA f32
//   [6586368  ..  6592512) bqkv f32
//   [6592512  .. 54040576) xb  : x bf16 -> ctx -> ff-chunk lo half
//   [54040576 ..101488640) qbuf: Q -> r1 -> ff-chunk hi half
//   [101488640..148936704) kbuf: K -> h
//   [148936704..196384768) vbuf: V -> s2
extern "C" void kernel_launch(void* const* d_in, const int* in_sizes, int n_in,
                              void* d_out, int out_size, void* d_ws, size_t ws_size,
                              hipStream_t stream)
{
  if (ws_size < WS_NEEDED) return;   // diagnostic bail: absmax will read 5.47

  const float* x   = (const float*)d_in[0];
  const int*   mask= (const int*)  d_in[1];
  const float* Wq  = (const float*)d_in[2];
  const float* bq  = (const float*)d_in[3];
  const float* Wk  = (const float*)d_in[4];
  const float* bk  = (const float*)d_in[5];
  const float* Wv  = (const float*)d_in[6];
  const float* bv  = (const float*)d_in[7];
  const float* Wo  = (const float*)d_in[8];
  const float* bo  = (const float*)d_in[9];
  const float* w1  = (const float*)d_in[10];
  const float* b1  = (const float*)d_in[11];
  const float* w2  = (const float*)d_in[12];
  const float* b2  = (const float*)d_in[13];
  const float* g1  = (const float*)d_in[14];
  const float* be1 = (const float*)d_in[15];
  const float* g2  = (const float*)d_in[16];
  const float* be2 = (const float*)d_in[17];

  char* ws = (char*)d_ws;
  u16*   wqkv  = (u16*)  (ws + 0);
  u16*   wo_b  = (u16*)  (ws + 1572864);
  u16*   w1_b  = (u16*)  (ws + 2097152);
  u16*   w2_b  = (u16*)  (ws + 4194304);
  float* biasA = (float*)(ws + 6291456);
  float* bqkv  = (float*)(ws + 6586368);
  u16*   xb    = (u16*)  (ws + 6592512);
  u16*   qbuf  = (u16*)  (ws + 54040576);
  u16*   kbuf  = qbuf + QKV_ELEMS;
  u16*   vbuf  = qbuf + 2*QKV_ELEMS;
  u16*   ffbuf = xb;                        // 94,896,128 B chunk (xb+qbuf)

  // dtype prep
  cast_bf16<<<128, 256, 0, stream>>>(Wq, wqkv,          32768);
  cast_bf16<<<128, 256, 0, stream>>>(Wk, wqkv + 262144, 32768);
  cast_bf16<<<128, 256, 0, stream>>>(Wv, wqkv + 524288, 32768);
  cast_bf16<<<128, 256, 0, stream>>>(Wo, wo_b,          32768);
  cast_bf16<<<512, 256, 0, stream>>>(w1, w1_b,         131072);
  cast_bf16<<<512, 256, 0, stream>>>(w2, w2_b,         131072);
  cast_bf16<<<11584,256, 0, stream>>>(x,  xb,         2965504);
  build_bias<<<288, 256, 0, stream>>>(mask, biasA);
  concat3<<<2, 256, 0, stream>>>(bq, bk, bv, bqkv);

  // QKV projection (scatter to [B,H,N,64] bf16, Q scaled by 1/8)
  {
    dim3 grid(12, 362);
    gemm_nt<0><<<grid, 256, 0, stream>>>(xb, wqkv, MTOT, 1536, 512, bqkv, qbuf, nullptr, nullptr);
  }
  // fused segment attention -> ctx (reuses xb region; x bf16 dead)
  attn_kernel<<<2048, 256, 0, stream>>>(qbuf, kbuf, vbuf, biasA, xb);
  // Wo projection + bo + x residual -> r1 (into qbuf; Q dead)
  {
    dim3 grid(4, 362);
    gemm_nt<1><<<grid, 256, 0, stream>>>(xb, wo_b, MTOT, 512, 512, bo, qbuf, x, nullptr);
  }
  // LN1 -> h (into kbuf; K dead)
  ln_kernel<0><<<11584, 256, 0, stream>>>(qbuf, g1, be1, kbuf);
  // FFN in 2 row-chunks; ffbuf aliases xb+qbuf (ctx and r1 dead)
  for (int c = 0; c < 2; ++c){
    const size_t ro = (size_t)c * MHALF * 512;
    {
      dim3 grid(16, 181);
      gemm_nt<2><<<grid, 256, 0, stream>>>(kbuf + ro, w1_b, MHALF, 2048, 512, b1, ffbuf, nullptr, nullptr);
    }
    {
      dim3 grid(4, 181);
      gemm_nt<3><<<grid, 256, 0, stream>>>(ffbuf, w2_b, MHALF, 512, 2048, b2, vbuf + ro, nullptr, kbuf + ro);
    }
  }
  // LN2 -> d_out (fp32)
  ln_kernel<1><<<11584, 256, 0, stream>>>(vbuf, g2, be2, d_out);
}

// Round 3
// 613.506 us; speedup vs baseline: 1.1590x; 1.1590x over previous
//
#include <hip/hip_runtime.h>
#include <math.h>

typedef unsigned short u16;
typedef unsigned int u32;
typedef short bf16x8 __attribute__((ext_vector_type(8)));
typedef unsigned short u16x8 __attribute__((ext_vector_type(8)));
typedef float f32x4 __attribute__((ext_vector_type(4)));

#define DEV static __device__ __forceinline__

#define BB 256
#define NN 181
#define DD 512
#define HH 8
#define DKk 64
#define DFF 2048
#define NPAD 192
#define MTOT (BB*NN)          // 46336
#define QKV_ELEMS (23724032u) // B*H*N*64
#define WS_NEEDED 196384768ull

DEV u16 f2bf(float f){
  u32 u = __float_as_uint(f);
  u32 r = (u + 0x7FFFu + ((u >> 16) & 1u)) >> 16;
  return (u16)r;
}
DEV float bf2f(u16 h){ return __uint_as_float(((u32)h) << 16); }
DEV bf16x8 as_bf(u16x8 v){ return __builtin_bit_cast(bf16x8, v); }

DEV void gl_lds16(const u16* g, u16* l){
  __builtin_amdgcn_global_load_lds(
      (const __attribute__((address_space(1))) unsigned int*)g,
      (__attribute__((address_space(3))) unsigned int*)l, 16, 0, 0);
}

// ---------------- cast fp32 -> bf16, 8 elems/thread ----------------
__global__ __launch_bounds__(256) void cast_bf16(const float* __restrict__ in,
                                                 u16* __restrict__ out, int n8){
  int i = blockIdx.x*256 + threadIdx.x;
  if (i >= n8) return;
  const float4* p = reinterpret_cast<const float4*>(in + (size_t)i*8);
  float4 a = p[0], b = p[1];
  u16x8 o;
  o[0]=f2bf(a.x); o[1]=f2bf(a.y); o[2]=f2bf(a.z); o[3]=f2bf(a.w);
  o[4]=f2bf(b.x); o[5]=f2bf(b.y); o[6]=f2bf(b.z); o[7]=f2bf(b.w);
  *reinterpret_cast<u16x8*>(out + (size_t)i*8) = o;
}

// ---------------- attention bias table [2][192][192] ----------------
__global__ __launch_bounds__(256) void build_bias(const int* __restrict__ mask,
                                                  float* __restrict__ biasA){
  int idx = blockIdx.x*256 + threadIdx.x;
  if (idx >= 2*NPAD*NPAD) return;
  int g = idx / (NPAD*NPAD);
  int rem = idx % (NPAD*NPAD);
  int q = rem / NPAD, k = rem % NPAD;
  float v;
  if (k >= NN) v = -INFINITY;
  else if (q >= NN) v = 0.f;
  else {
    bool qv = q < 121, kv = k < 121;
    bool allowed = (g == 0) ? (qv != kv) : (qv == kv);
    if (!allowed) v = -INFINITY;
    else {
      int mb = (g == 0 && !qv) ? mask[k*NN + q]
                               : mask[q*NN + k];
      v = mb ? -1e9f : 0.f;
    }
  }
  biasA[idx] = v;
}

__global__ __launch_bounds__(256) void concat3(const float* __restrict__ a,
                                               const float* __restrict__ b,
                                               const float* __restrict__ c,
                                               float* __restrict__ out){
  int i = blockIdx.x*256 + threadIdx.x;
  if (i < 512){ out[i] = a[i]; out[512+i] = b[i]; out[1024+i] = c[i]; }
}

// ================= 256x256 8-phase GEMM, C = A(MxK) * B(NxK)^T =================
// 512 thr = 8 waves (2M x 4N), BK=64, dbuf LDS 128KB, st_16x32 swizzle,
// counted vmcnt(4), setprio around MFMA. EPI as before.
#define STAGE(SB, SO, SH, KT) do { \
    int kt_ = (KT); if (kt_ >= ntiles) kt_ = 0; \
    const u16* s_ = ((SO) == 0 ? stA : stB) + (size_t)(SH)*128*K + kt_*64; \
    gl_lds16(s_, &ldsT[SB][SO][SH][wave*512]); \
    gl_lds16(s_ + (size_t)64*K, &ldsT[SB][SO][SH][wave*512 + 4096]); \
  } while(0)

#define PHASE(CB, MH, NH, SB, SO, SH, KT, VM) do { \
    bf16x8 af_[4][2], bg_[2][2]; \
    const u16* ap_ = &ldsT[CB][0][MH][0] + aRdBase; \
    const u16* bp_ = &ldsT[CB][1][NH][0] + bRdBase; \
    _Pragma("unroll") for (int m_=0; m_<4; ++m_) \
      _Pragma("unroll") for (int k_=0; k_<2; ++k_) \
        af_[m_][k_] = *reinterpret_cast<const bf16x8*>(ap_ + m_*2048 + k_*512); \
    _Pragma("unroll") for (int n_=0; n_<2; ++n_) \
      _Pragma("unroll") for (int k_=0; k_<2; ++k_) \
        bg_[n_][k_] = *reinterpret_cast<const bf16x8*>(bp_ + n_*4096 + k_*512); \
    STAGE(SB, SO, SH, KT); \
    if (VM) asm volatile("s_waitcnt vmcnt(4)" ::: "memory"); \
    __builtin_amdgcn_sched_barrier(0); \
    __builtin_amdgcn_s_barrier(); \
    __builtin_amdgcn_sched_barrier(0); \
    __builtin_amdgcn_s_setprio(1); \
    _Pragma("unroll") for (int m_=0; m_<4; ++m_) \
      _Pragma("unroll") for (int n_=0; n_<2; ++n_) \
        _Pragma("unroll") for (int k_=0; k_<2; ++k_) \
          acc[(MH)*4+m_][(NH)*2+n_] = __builtin_amdgcn_mfma_f32_16x16x32_bf16( \
              af_[m_][k_], bg_[n_][k_], acc[(MH)*4+m_][(NH)*2+n_], 0,0,0); \
    __builtin_amdgcn_s_setprio(0); \
    __builtin_amdgcn_sched_barrier(0); \
    __builtin_amdgcn_s_barrier(); \
    __builtin_amdgcn_sched_barrier(0); \
  } while(0)

template<int EPI>
__global__ __launch_bounds__(512) void gemm8(
    const u16* __restrict__ A, const u16* __restrict__ Bw,
    int K, int N,
    const float* __restrict__ bias,
    u16* __restrict__ outb,
    const float* __restrict__ resf,
    const u16* __restrict__ resb)
{
  __shared__ u16 ldsT[2][2][2][8192];   // [buf][A/B][half][128x64] 128 KiB
  const int tid = threadIdx.x, lane = tid & 63, wave = tid >> 6;
  const int lo = lane & 15, hi = lane >> 4;
  const int wm = wave >> 2, wn = wave & 3;
  const int mt = blockIdx.y, ntb = blockIdx.x;
  const int ntiles = K >> 6, niter = ntiles >> 1;

  // staging: thread covers physical LDS bytes P = tid*16 (+ j*8192);
  // inverse st_16x32 swizzle -> logical (row pr, col pc) of the half-tile
  const int pr = ((tid >> 7) << 4) | ((tid >> 2) & 15);
  const int pc = (((tid >> 6) & 1) << 5) | (((tid & 3) * 8) ^ (((tid >> 5) & 1) << 4));
  const u16* stA = A  + (size_t)(mt*256 + pr) * K + pc;
  const u16* stB = Bw + (size_t)(ntb*256 + pr) * K + pc;
  // swizzled fragment-read lane base (elements)
  const int aRdBase = wm*1024 + lo*32 + ((hi*8) ^ ((lo & 8) << 1));
  const int bRdBase = wn*1024 + lo*32 + ((hi*8) ^ ((lo & 8) << 1));

  f32x4 acc[8][4];
  #pragma unroll
  for (int f=0; f<8; ++f)
    #pragma unroll
    for (int n=0; n<4; ++n) acc[f][n] = f32x4{0.f,0.f,0.f,0.f};

  // prologue: tile0 all 4 halves + tile1 A0,B0 (12 loads), wait 8 landed
  STAGE(0,0,0, 0); STAGE(0,1,0, 0); STAGE(0,0,1, 0); STAGE(0,1,1, 0);
  STAGE(1,0,0, 1); STAGE(1,1,0, 1);
  asm volatile("s_waitcnt vmcnt(4)" ::: "memory");
  __builtin_amdgcn_sched_barrier(0);
  __builtin_amdgcn_s_barrier();
  __builtin_amdgcn_sched_barrier(0);

  for (int i = 0; i < niter; ++i){
    const int v1 = 2*i+1, u2 = 2*i+2, v2 = 2*i+3;
    PHASE(0,0,0, 1,0,1, v1, 0);   // compute u(0,0); stage A1(v)
    PHASE(0,0,1, 1,1,1, v1, 0);   // u(0,1); B1(v)
    PHASE(0,1,0, 0,0,0, u2, 0);   // u(1,0); A0(u+2)
    PHASE(0,1,1, 0,1,0, u2, 1);   // u(1,1); B0(u+2); vmcnt
    PHASE(1,0,0, 0,0,1, u2, 0);   // v(0,0); A1(u+2)
    PHASE(1,0,1, 0,1,1, u2, 0);   // v(0,1); B1(u+2)
    PHASE(1,1,0, 1,0,0, v2, 0);   // v(1,0); A0(v+2)
    PHASE(1,1,1, 1,1,0, v2, 1);   // v(1,1); B0(v+2); vmcnt
  }
  asm volatile("s_waitcnt vmcnt(0)" ::: "memory");

  // epilogue: row = mt*256 + wm*16 + f*32 + hi*4 + rg; col = ntb*256 + wn*16 + n*64 + lo
  float bv[4];
  #pragma unroll
  for (int n=0; n<4; ++n) bv[n] = bias[ntb*256 + wn*16 + n*64 + lo];
  #pragma unroll
  for (int f=0; f<8; ++f){
    #pragma unroll
    for (int rg=0; rg<4; ++rg){
      const int row = mt*256 + wm*16 + f*32 + hi*4 + rg;
      if constexpr (EPI == 0){
        const int bi = row / NN, ni = row - bi*NN;
        #pragma unroll
        for (int n=0; n<4; ++n){
          const int gcol = ntb*256 + wn*16 + n*64 + lo;
          float v = acc[f][n][rg] + bv[n];
          int which = gcol >> 9;
          int hh = (gcol >> 6) & 7;
          int d  = gcol & 63;
          if (which == 0) v *= 0.125f;
          outb[(size_t)which*QKV_ELEMS + (((size_t)bi*HH + hh)*NN + ni)*DKk + d] = f2bf(v);
        }
      } else {
        #pragma unroll
        for (int n=0; n<4; ++n){
          const int gcol = ntb*256 + wn*16 + n*64 + lo;
          float v = acc[f][n][rg] + bv[n];
          if constexpr (EPI == 1){
            v += resf[(size_t)row*N + gcol];
          } else if constexpr (EPI == 3){
            v += bf2f(resb[(size_t)row*N + gcol]);
          } else {
            v = fmaxf(v, 0.f);
          }
          outb[(size_t)row*N + gcol] = f2bf(v);
        }
      }
    }
  }
}

// ---------------- fused segment attention (unchanged, verified r2) ----------------
__global__ __launch_bounds__(256) void attn_kernel(
    const u16* __restrict__ Qg, const u16* __restrict__ Kg, const u16* __restrict__ Vg,
    const float* __restrict__ biasA, u16* __restrict__ ctx)
{
  __shared__ u16 Kb[NPAD*72];
  __shared__ u16 Vt[64*200];
  __shared__ u16 Pl[4*16*200];
  const int tid = threadIdx.x, lane = tid & 63, wave = tid >> 6;
  const int lo = lane & 15, hi = lane >> 4;
  const int bh = blockIdx.x;
  const int h = bh & 7, g = h >> 2, b = bh >> 3;
  const size_t base = (size_t)bh * NN * DKk;

  #pragma unroll
  for (int it=0; it<6; ++it){
    int row = it*32 + (tid >> 3);
    int cb = (tid & 7)*8;
    u16x8 val = {0,0,0,0,0,0,0,0};
    if (row < NN) val = *reinterpret_cast<const u16x8*>(Kg + base + (size_t)row*DKk + cb);
    *reinterpret_cast<u16x8*>(&Kb[row*72 + cb]) = val;
  }
  #pragma unroll
  for (int it=0; it<6; ++it){
    int row = it*32 + (tid >> 3);
    int cb = (tid & 7)*8;
    u16x8 val = {0,0,0,0,0,0,0,0};
    if (row < NN) val = *reinterpret_cast<const u16x8*>(Vg + base + (size_t)row*DKk + cb);
    *reinterpret_cast<u16x8*>(&Pl[row*64 + cb]) = val;
  }
  __syncthreads();
  #pragma unroll
  for (int j=0;j<6;++j){
    int task = j*256 + tid;
    int d = task & 63;
    int nc = task >> 6;
    u16x8 tv;
    #pragma unroll
    for (int i=0;i<8;++i) tv[i] = Pl[(nc*8+i)*64 + d];
    *reinterpret_cast<u16x8*>(&Vt[d*200 + nc*8]) = tv;
  }
  __syncthreads();

  u16* pw = Pl + wave*16*200;

  for (int rb = wave; rb < 12; rb += 4){
    const int q0 = rb*16;
    const int qrow = q0 + lo;
    bf16x8 qa[2];
    #pragma unroll
    for (int kk=0;kk<2;++kk){
      u16x8 val = {0,0,0,0,0,0,0,0};
      if (qrow < NN) val = *reinterpret_cast<const u16x8*>(Qg + base + (size_t)qrow*DKk + kk*32 + hi*8);
      qa[kk] = as_bf(val);
    }
    f32x4 s[12];
    #pragma unroll
    for (int c=0;c<12;++c){
      f32x4 a = f32x4{0.f,0.f,0.f,0.f};
      #pragma unroll
      for (int kk=0;kk<2;++kk){
        bf16x8 kb = *reinterpret_cast<const bf16x8*>(&Kb[(c*16+lo)*72 + kk*32 + hi*8]);
        a = __builtin_amdgcn_mfma_f32_16x16x32_bf16(qa[kk], kb, a, 0,0,0);
      }
      s[c] = a;
    }
    const float* brow = biasA + ((size_t)g*NPAD + q0 + hi*4)*NPAD + lo;
    #pragma unroll
    for (int r=0;r<4;++r)
      #pragma unroll
      for (int c=0;c<12;++c)
        s[c][r] += brow[r*NPAD + c*16];
    float inv[4];
    #pragma unroll
    for (int r=0;r<4;++r){
      float m = s[0][r];
      #pragma unroll
      for (int c=1;c<12;++c) m = fmaxf(m, s[c][r]);
      #pragma unroll
      for (int off=1; off<16; off<<=1) m = fmaxf(m, __shfl_xor(m, off, 64));
      float t = 0.f;
      #pragma unroll
      for (int c=0;c<12;++c){ float e = __expf(s[c][r] - m); s[c][r] = e; t += e; }
      #pragma unroll
      for (int off=1; off<16; off<<=1) t += __shfl_xor(t, off, 64);
      inv[r] = 1.0f / t;
    }
    #pragma unroll
    for (int c=0;c<12;++c)
      #pragma unroll
      for (int r=0;r<4;++r)
        pw[(hi*4+r)*200 + c*16 + lo] = f2bf(s[c][r] * inv[r]);
    asm volatile("s_waitcnt lgkmcnt(0)" ::: "memory");
    __builtin_amdgcn_sched_barrier(0);
    bf16x8 pa[6];
    #pragma unroll
    for (int c6=0;c6<6;++c6)
      pa[c6] = *reinterpret_cast<const bf16x8*>(&pw[lo*200 + c6*32 + hi*8]);
    #pragma unroll
    for (int dt=0;dt<4;++dt){
      f32x4 a = f32x4{0.f,0.f,0.f,0.f};
      #pragma unroll
      for (int c6=0;c6<6;++c6){
        bf16x8 vb = *reinterpret_cast<const bf16x8*>(&Vt[(dt*16+lo)*200 + c6*32 + hi*8]);
        a = __builtin_amdgcn_mfma_f32_16x16x32_bf16(pa[c6], vb, a, 0,0,0);
      }
      #pragma unroll
      for (int r=0;r<4;++r){
        int q = q0 + hi*4 + r;
        if (q < NN)
          ctx[((size_t)b*NN + q)*DD + h*DKk + dt*16 + lo] = f2bf(a[r]);
      }
    }
  }
}

// ---------------- LayerNorm over D=512, one wave per row ----------------
template<int OUTF32>
__global__ __launch_bounds__(256) void ln_kernel(
    const u16* __restrict__ in, const float* __restrict__ gamma,
    const float* __restrict__ beta, void* __restrict__ outp)
{
  const int row = blockIdx.x*4 + (threadIdx.x >> 6);
  const int lane = threadIdx.x & 63;
  u16x8 rv = *reinterpret_cast<const u16x8*>(in + (size_t)row*512 + lane*8);
  float x[8]; float s = 0.f, s2 = 0.f;
  #pragma unroll
  for (int i=0;i<8;++i){ x[i] = bf2f(rv[i]); s += x[i]; s2 += x[i]*x[i]; }
  #pragma unroll
  for (int off=32; off>=1; off>>=1){ s += __shfl_xor(s, off, 64); s2 += __shfl_xor(s2, off, 64); }
  const float mu = s * (1.f/512.f);
  const float var = s2 * (1.f/512.f) - mu*mu;
  const float rstd = rsqrtf(var + 1e-5f);
  float4 ga = *reinterpret_cast<const float4*>(gamma + lane*8);
  float4 gb = *reinterpret_cast<const float4*>(gamma + lane*8 + 4);
  float4 ba = *reinterpret_cast<const float4*>(beta + lane*8);
  float4 bb = *reinterpret_cast<const float4*>(beta + lane*8 + 4);
  float gg[8] = {ga.x,ga.y,ga.z,ga.w,gb.x,gb.y,gb.z,gb.w};
  float bt[8] = {ba.x,ba.y,ba.z,ba.w,bb.x,bb.y,bb.z,bb.w};
  if constexpr (OUTF32){
    float o[8];
    #pragma unroll
    for (int i=0;i<8;++i) o[i] = (x[i]-mu)*rstd*gg[i] + bt[i];
    float4* op = reinterpret_cast<float4*>((float*)outp + (size_t)row*512 + lane*8);
    op[0] = make_float4(o[0],o[1],o[2],o[3]);
    op[1] = make_float4(o[4],o[5],o[6],o[7]);
  } else {
    u16x8 o;
    #pragma unroll
    for (int i=0;i<8;++i) o[i] = f2bf((x[i]-mu)*rstd*gg[i] + bt[i]);
    *reinterpret_cast<u16x8*>((u16*)outp + (size_t)row*512 + lane*8) = o;
  }
}

// ---------------- launch ----------------
// ws map (total 196,384,768 B):
//   [0        ..  2097152) w1_b bf16            (live through FF1)
//   [2097152  ..  4194304) w2_b bf16            (live through FF2)
//   [4194304  ..  5767168) wqkv bf16            (dead after QKV)
//   [5767168  ..  6291456) wo_b bf16            (dead after Wo)
//   [6291456  ..  6586368) biasA f32            (dead after attn)
//   [6586368  ..  6592512) bqkv f32             (dead after QKV)
//   [6592512  .. 54040576) xb  : x bf16 -> ctx  (dead after Wo)
//   [54040576 ..101488640) qbuf: Q -> r1        (dead after LN1)
//   [101488640..148936704) kbuf: K -> h
//   [148936704..196384768) vbuf: V -> s2
//   ffbuf = ws+4194304, 95,420,416 B max (91-tile chunk) -> ends 99,614,720 < kbuf
extern "C" void kernel_launch(void* const* d_in, const int* in_sizes, int n_in,
                              void* d_out, int out_size, void* d_ws, size_t ws_size,
                              hipStream_t stream)
{
  if (ws_size < WS_NEEDED) return;

  const float* x   = (const float*)d_in[0];
  const int*   mask= (const int*)  d_in[1];
  const float* Wq  = (const float*)d_in[2];
  const float* bq  = (const float*)d_in[3];
  const float* Wk  = (const float*)d_in[4];
  const float* bk  = (const float*)d_in[5];
  const float* Wv  = (const float*)d_in[6];
  const float* bv  = (const float*)d_in[7];
  const float* Wo  = (const float*)d_in[8];
  const float* bo  = (const float*)d_in[9];
  const float* w1  = (const float*)d_in[10];
  const float* b1  = (const float*)d_in[11];
  const float* w2  = (const float*)d_in[12];
  const float* b2  = (const float*)d_in[13];
  const float* g1  = (const float*)d_in[14];
  const float* be1 = (const float*)d_in[15];
  const float* g2  = (const float*)d_in[16];
  const float* be2 = (const float*)d_in[17];

  char* ws = (char*)d_ws;
  u16*   w1_b  = (u16*)  (ws + 0);
  u16*   w2_b  = (u16*)  (ws + 2097152);
  u16*   wqkv  = (u16*)  (ws + 4194304);
  u16*   wo_b  = (u16*)  (ws + 5767168);
  float* biasA = (float*)(ws + 6291456);
  float* bqkv  = (float*)(ws + 6586368);
  u16*   xb    = (u16*)  (ws + 6592512);
  u16*   qbuf  = (u16*)  (ws + 54040576);
  u16*   kbuf  = qbuf + QKV_ELEMS;
  u16*   vbuf  = qbuf + 2*QKV_ELEMS;
  u16*   ffbuf = (u16*)  (ws + 4194304);

  // dtype prep
  cast_bf16<<<128, 256, 0, stream>>>(Wq, wqkv,          32768);
  cast_bf16<<<128, 256, 0, stream>>>(Wk, wqkv + 262144, 32768);
  cast_bf16<<<128, 256, 0, stream>>>(Wv, wqkv + 524288, 32768);
  cast_bf16<<<128, 256, 0, stream>>>(Wo, wo_b,          32768);
  cast_bf16<<<512, 256, 0, stream>>>(w1, w1_b,         131072);
  cast_bf16<<<512, 256, 0, stream>>>(w2, w2_b,         131072);
  cast_bf16<<<11584,256, 0, stream>>>(x,  xb,         2965504);
  build_bias<<<288, 256, 0, stream>>>(mask, biasA);
  concat3<<<2, 256, 0, stream>>>(bq, bk, bv, bqkv);

  // QKV projection (scatter to [B,H,N,64] bf16, Q scaled by 1/8)
  gemm8<0><<<dim3(6,181), 512, 0, stream>>>(xb, wqkv, 512, 1536, bqkv, qbuf, nullptr, nullptr);
  // fused segment attention -> ctx (xb region)
  attn_kernel<<<2048, 256, 0, stream>>>(qbuf, kbuf, vbuf, biasA, xb);
  // Wo projection + bo + x residual -> r1 (qbuf)
  gemm8<1><<<dim3(2,181), 512, 0, stream>>>(xb, wo_b, 512, 512, bo, qbuf, x, nullptr);
  // LN1 -> h (kbuf)
  ln_kernel<0><<<11584, 256, 0, stream>>>(qbuf, g1, be1, kbuf);
  // FFN in 2 chunks (91 + 90 tiles of 256 rows); ffbuf overlays dead regions
  {
    gemm8<2><<<dim3(8,91), 512, 0, stream>>>(kbuf, w1_b, 512, 2048, b1, ffbuf, nullptr, nullptr);
    gemm8<3><<<dim3(2,91), 512, 0, stream>>>(ffbuf, w2_b, 2048, 512, b2, vbuf, nullptr, kbuf);
    const size_t ro = (size_t)23296 * 512;
    gemm8<2><<<dim3(8,90), 512, 0, stream>>>(kbuf + ro, w1_b, 512, 2048, b1, ffbuf, nullptr, nullptr);
    gemm8<3><<<dim3(2,90), 512, 0, stream>>>(ffbuf, w2_b, 2048, 512, b2, vbuf + ro, nullptr, kbuf + ro);
  }
  // LN2 -> d_out (fp32)
  ln_kernel<1><<<11584, 256, 0, stream>>>(vbuf, g2, be2, d_out);
}